// Round 4
// baseline (519.355 us; speedup 1.0000x reference)
//
#include <hip/hip_runtime.h>
#include <hip/hip_bf16.h>
#include <math.h>

#define B_ 2
#define L_ 2048
#define C_ 1024
#define H_ 16
#define D_ 64

typedef __attribute__((ext_vector_type(8))) short short8;   // 8 bf16 = 16B
typedef __attribute__((ext_vector_type(4))) float float4v;

__device__ inline short f2bs(float f) {
    union { __hip_bfloat16 h; short s; } u; u.h = __float2bfloat16(f); return u.s;
}

// async 16B global→LDS DMA (dest = wave-uniform base + lane*16)
#define GL2LDS(gp, lp)                                                         \
    __builtin_amdgcn_global_load_lds(                                          \
        (const __attribute__((address_space(1))) void*)(gp),                   \
        (__attribute__((address_space(3))) void*)(lp), 16, 0, 0)

// ---------------------------------------------------------------------------
// k_mod2: m = silu(mod) @ w_mod + b_mod, split-K (4 segs of 256) + atomicAdd.
__global__ __launch_bounds__(256) void k_mod2(const float* __restrict__ mod,
                                              const float* __restrict__ w_mod,
                                              const float* __restrict__ b_mod,
                                              float* __restrict__ m_out) {
    __shared__ float a_s[2][256];
    const int t = threadIdx.x;
    const int seg = blockIdx.y;
    for (int i = t; i < 512; i += 256) {
        float a = mod[(i >> 8) * C_ + seg * 256 + (i & 255)];
        a_s[i >> 8][i & 255] = a / (1.f + __expf(-a));  // silu
    }
    __syncthreads();
    int j = blockIdx.x * 256 + t;  // 0..6143
    float acc0 = (seg == 0) ? b_mod[j] : 0.f;
    float acc1 = acc0;
    for (int k = 0; k < 256; ++k) {
        float w = w_mod[(size_t)(seg * 256 + k) * (6 * C_) + j];
        acc0 += a_s[0][k] * w;
        acc1 += a_s[1][k] * w;
    }
    atomicAdd(&m_out[j], acc0);
    atomicAdd(&m_out[6 * C_ + j], acc1);
}

// ---------------------------------------------------------------------------
// k_wt_all: all four weight transposes (fp32 [K][N] → bf16 [N][K]) in ONE
// launch. Flat grid of 3072 64x64 tiles: [0,768) qkv | [768,1024) proj |
// [1024,2048) fc1 | [2048,3072) fc2.
__global__ __launch_bounds__(256) void k_wt_all(
        const float* __restrict__ w_qkv, const float* __restrict__ w_proj,
        const float* __restrict__ w_fc1, const float* __restrict__ w_fc2,
        short* __restrict__ wqkvT, short* __restrict__ wprojT,
        short* __restrict__ wfc1T, short* __restrict__ wfc2T) {
    __shared__ short T[64][72];
    int id = blockIdx.x;
    const float* W; short* WT; int K, N;
    if (id < 768)       {             W = w_qkv;  WT = wqkvT;  K = C_;     N = 3 * C_; }
    else if (id < 1024) { id -= 768;  W = w_proj; WT = wprojT; K = C_;     N = C_;     }
    else if (id < 2048) { id -= 1024; W = w_fc1;  WT = wfc1T;  K = C_;     N = 4 * C_; }
    else                { id -= 2048; W = w_fc2;  WT = wfc2T;  K = 4 * C_; N = C_;     }
    const int nb = N >> 6;
    const int n0 = (id % nb) * 64, k0 = (id / nb) * 64;
    const int t = threadIdx.x;
    {
        int kr = t >> 2, nc = (t & 3) * 16;
        const float* src = W + (size_t)(k0 + kr) * N + n0 + nc;
#pragma unroll
        for (int j = 0; j < 16; ++j) T[kr][nc + j] = f2bs(src[j]);
    }
    __syncthreads();
    {
        int nr = t >> 2, kc = (t & 3) * 16;
        short8 o0, o1;
#pragma unroll
        for (int j = 0; j < 8; ++j) { o0[j] = T[kc + j][nr]; o1[j] = T[kc + 8 + j][nr]; }
        short* dst = WT + (size_t)(n0 + nr) * K + k0 + kc;
        *(short8*)dst = o0;
        *(short8*)(dst + 8) = o1;
    }
}

// ---------------------------------------------------------------------------
// k_vt: per-head V transpose. qkv [4096,3072] → vt [bh=32][d=64][L=2048] bf16.
__global__ __launch_bounds__(256) void k_vt(const __hip_bfloat16* __restrict__ qkv,
                                            short* __restrict__ vt) {
    __shared__ short T[64][72];
    const int t = threadIdx.x;
    const int kt = blockIdx.x * 64;
    const int bh = blockIdx.y;
    const int h = bh & (H_ - 1), b = bh >> 4;
    const __hip_bfloat16* src = qkv + ((size_t)(b * L_ + kt)) * (3 * C_) + 2 * C_ + h * D_;
    {
        int kr = t >> 2, dg = (t & 3) * 16;
        const short8* s = (const short8*)(src + (size_t)kr * (3 * C_) + dg);
        *(short8*)&T[kr][dg] = s[0];
        *(short8*)&T[kr][dg + 8] = s[1];
    }
    __syncthreads();
    {
        int dr = t >> 2, kg = (t & 3) * 16;
        short8 o0, o1;
#pragma unroll
        for (int j = 0; j < 8; ++j) { o0[j] = T[kg + j][dr]; o1[j] = T[kg + 8 + j][dr]; }
        short* dst = vt + ((size_t)bh * D_ + dr) * L_ + kt + kg;
        *(short8*)dst = o0;
        *(short8*)(dst + 8) = o1;
    }
}

// ---------------------------------------------------------------------------
// Kernel 2: LayerNorm (eps 1e-6, no affine) + adaLN modulate → bf16 h
__global__ __launch_bounds__(256) void k_ln_mod(const float* __restrict__ x,
                                                const float* __restrict__ mvec,
                                                int off_sh, int off_sc,
                                                __hip_bfloat16* __restrict__ h_out) {
    int row = blockIdx.x;       // 0..4095
    int b = row / L_;
    int t = threadIdx.x;
    float v[4];
    float s = 0.f, ss = 0.f;
#pragma unroll
    for (int i = 0; i < 4; ++i) {
        int c = t + i * 256;
        float val = x[(size_t)row * C_ + c];
        v[i] = val; s += val; ss += val * val;
    }
#pragma unroll
    for (int o = 32; o; o >>= 1) { s += __shfl_xor(s, o); ss += __shfl_xor(ss, o); }
    __shared__ float red[2][4];
    int wid = t >> 6, lane = t & 63;
    if (lane == 0) { red[0][wid] = s; red[1][wid] = ss; }
    __syncthreads();
    s  = red[0][0] + red[0][1] + red[0][2] + red[0][3];
    ss = red[1][0] + red[1][1] + red[1][2] + red[1][3];
    float mean = s * (1.f / C_);
    float var  = ss * (1.f / C_) - mean * mean;
    float rstd = rsqrtf(var + 1e-6f);
#pragma unroll
    for (int i = 0; i < 4; ++i) {
        int c = t + i * 256;
        float sc = mvec[b * (6 * C_) + off_sc + c];
        float sh = mvec[b * (6 * C_) + off_sh + c];
        float hn = (v[i] - mean) * rstd;
        h_out[(size_t)row * C_ + c] = __float2bfloat16(hn * (1.f + sc) + sh);
    }
}

// ---------------------------------------------------------------------------
// Shared GEMM epilogue
__device__ inline void gemm_epilogue(float v, int m, int n, int N, int act, int emode,
                                     const float* __restrict__ gate,
                                     const float* __restrict__ resid_f,
                                     __hip_bfloat16* __restrict__ out_bf,
                                     float* __restrict__ out_f) {
    if (act == 1) v = 0.5f * v * (1.f + erff(v * 0.70710678118654752440f));
    if (emode == 2) {
        float g = gate[(m >> 11) * (6 * C_) + n];
        v = resid_f[(size_t)m * N + n] + v * g;
    }
    if (out_f) out_f[(size_t)m * N + n] = v;
    else       out_bf[(size_t)m * N + n] = __float2bfloat16(v);
}

// ---------------------------------------------------------------------------
// k_gemm_async: A[M,K](bf16) @ WT[N,K](bf16 pre-transposed).
// v5 (this round): T4 counted-vmcnt ring, FOUR buffers, prefetch DISTANCE 3.
// Round-3 post-mortem: distance-2 @BK=32 = same in-flight TIME as dbuf@BK=64
// (zero added latency coverage), and the `^(row&3)` swizzle was a 4-way
// bank conflict (even rows only hit 2 of 4 chunk slots). Fixes:
//   * distance 3: a tile is in flight for ~3 steps (~1100 cyc) > ~900-cyc
//     worst-case load latency; steady-state wait = vmcnt(2*NLOADS), tail
//     2N → N → 0. Never drains to 0 mid-loop (m218 mechanism).
//   * swizzle ^((row>>1)&3): 16-lane quad-group → 8 (row-parity, slot)
//     pairs × 2 lanes = 2-way = free. Staging dest stays DMA-linear.
// LDS: 64KB (128² tiles, 2 blk/CU) / 48KB (128×64, 3 blk/CU). Requires
// K >= 128 (nt >= 4): true for all four call sites (K = 1024 or 4096).
template<int WM, int WN, int MI, int NI>
__global__ __launch_bounds__(256) void k_gemm_async(
        const __hip_bfloat16* __restrict__ A, int lda,
        const short* __restrict__ WT, int ldw,
        const float* __restrict__ bias,
        int M, int N, int K, int act, int emode,
        const float* __restrict__ gate,
        const float* __restrict__ resid_f,
        __hip_bfloat16* __restrict__ out_bf,
        float* __restrict__ out_f) {
    constexpr int BM = WM * MI * 16;
    constexpr int BN = WN * NI * 16;
    constexpr int NLOADS = BM / 64 + BN / 64;   // gl_lds insts per stage per thread
    __shared__ __align__(16) short A_lds[4][BM * 32];
    __shared__ __align__(16) short B_lds[4][BN * 32];
    const int t = threadIdx.x;
    const int lane = t & 63;
    const int w = t >> 6;
    const int wm = w / WN, wn = w % WN;
    const int quad = lane >> 4, l16 = lane & 15;
    const int m0 = blockIdx.y * BM;
    const int n0 = blockIdx.x * BN;

    auto stage = [&](int buf, int k0) {
#pragma unroll
        for (int rep = 0; rep < BM / 64; ++rep) {
            int p = rep * 256 + t;                 // phys chunk id (16B chunks)
            int row = p >> 2;
            int g = (p & 3) ^ ((row >> 1) & 3);    // logical k-group
            const __hip_bfloat16* gp = A + (size_t)(m0 + row) * lda + k0 + g * 8;
            GL2LDS(gp, &A_lds[buf][(rep * 256 + (t & ~63)) * 8]);
        }
#pragma unroll
        for (int rep = 0; rep < BN / 64; ++rep) {
            int p = rep * 256 + t;
            int row = p >> 2;
            int g = (p & 3) ^ ((row >> 1) & 3);
            const short* gp = WT + (size_t)(n0 + row) * ldw + k0 + g * 8;
            GL2LDS(gp, &B_lds[buf][(rep * 256 + (t & ~63)) * 8]);
        }
    };

    float4v acc[MI][NI] = {};
    const int nt = K >> 5;      // >= 4 at every call site

    // prologue: tiles 0,1,2 in flight; counted wait → tile 0 landed only
    stage(0, 0);
    stage(1, 32);
    stage(2, 64);
    asm volatile("s_waitcnt vmcnt(%0)" :: "n"(2 * NLOADS) : "memory");
    __builtin_amdgcn_sched_barrier(0);
    __builtin_amdgcn_s_barrier();
    __builtin_amdgcn_sched_barrier(0);

    for (int kt = 0; kt < nt; ++kt) {
        const int cur = kt & 3;
        // prefetch tile kt+3 into buf[(kt+3)&3] = buf read at step kt-1
        // (its readers passed the end-of-step-(kt-1) barrier)
        if (kt + 3 < nt) stage((kt + 3) & 3, (kt + 3) << 5);

        // ---- fragments + MFMA from buf[cur] (one 32-deep k-slab) ----
        short8 af[MI], bfr[NI];
#pragma unroll
        for (int mi = 0; mi < MI; ++mi) {
            int r = wm * MI * 16 + mi * 16 + l16;
            af[mi] = *(const short8*)(&A_lds[cur][(r * 4 + (quad ^ ((r >> 1) & 3))) * 8]);
        }
#pragma unroll
        for (int ni = 0; ni < NI; ++ni) {
            int r = wn * NI * 16 + ni * 16 + l16;
            bfr[ni] = *(const short8*)(&B_lds[cur][(r * 4 + (quad ^ ((r >> 1) & 3))) * 8]);
        }
#pragma unroll
        for (int mi = 0; mi < MI; ++mi)
#pragma unroll
            for (int ni = 0; ni < NI; ++ni)
                acc[mi][ni] = __builtin_amdgcn_mfma_f32_16x16x32_bf16(
                    af[mi], bfr[ni], acc[mi][ni], 0, 0, 0);

        // counted wait: guarantee tile kt+1 landed; newer stages stay in
        // flight across the barrier (never vmcnt(0) until the tail).
        if (kt + 1 < nt) {
            if (kt + 4 <= nt)           // stage(kt+3) issued this step
                asm volatile("s_waitcnt vmcnt(%0)" :: "n"(2 * NLOADS) : "memory");
            else if (kt + 3 == nt)      // outstanding ⊆ {kt+1, kt+2}
                asm volatile("s_waitcnt vmcnt(%0)" :: "n"(NLOADS) : "memory");
            else                        // kt == nt-2: only tile kt+1 left
                asm volatile("s_waitcnt vmcnt(0)" ::: "memory");
            __builtin_amdgcn_sched_barrier(0);
            __builtin_amdgcn_s_barrier();
            __builtin_amdgcn_sched_barrier(0);
        }
    }

#pragma unroll
    for (int mi = 0; mi < MI; ++mi)
#pragma unroll
        for (int ni = 0; ni < NI; ++ni)
#pragma unroll
            for (int r = 0; r < 4; ++r) {
                int m = m0 + wm * MI * 16 + mi * 16 + quad * 4 + r;
                int n = n0 + wn * NI * 16 + ni * 16 + l16;
                float v = acc[mi][ni][r] + (bias ? bias[n] : 0.f);
                gemm_epilogue(v, m, n, N, act, emode, gate, resid_f, out_bf, out_f);
            }
}

// ---------------------------------------------------------------------------
// Kernel 4: flash attention, MFMA, shift-softmax (no max tracking: constant
// shift cancels in Σpv/Σp; scores bounded |s|≲6 ⇒ no overflow). Row-sums l
// via extra MFMA against all-ones B-frag.
//
// 512 threads / 8 waves, q_blk=128, double-buffered K/V LDS with T14
// async-stage split: next-tile K/V chunks loaded into REGISTERS at the top
// of the tile (global latency hides under QK/softmax/PV), written to the
// alternate LDS buffer after compute, ONE barrier per tile. All LDS strides
// = 72 shorts (144B, 16B-aligned rows → true ds_read_b128). Grid 512 =
// 2 blocks/CU, XCD-chunked block swizzle for L2 locality.
__global__ __launch_bounds__(512) void k_attn(const __hip_bfloat16* __restrict__ qkv,
                                              const short* __restrict__ vt,
                                              __hip_bfloat16* __restrict__ o) {
    __shared__ __align__(16) short K_lds[2][64 * 72];   // [buf][key][d]
    __shared__ __align__(16) short V_lds[2][64 * 72];   // [buf][d][key]
    __shared__ __align__(16) short P_lds[8][16 * 72];   // per wave: [q][key]
    const int t = threadIdx.x;
    const int lane = t & 63;
    const int w = t >> 6;                   // 0..7
    const int quad = lane >> 4, l16 = lane & 15;

    // XCD-chunked bijective swizzle: 512 wgs, 8 XCDs, 64 contiguous per XCD.
    const int raw = blockIdx.x;
    const int blk = (raw & 7) * 64 + (raw >> 3);
    const int bh = blk >> 4;                // 0..31 (4 bh per XCD chunk)
    const int q_blk = (blk & 15) * 128;
    const int h = bh & (H_ - 1);
    const int b = bh >> 4;

    const size_t stride = 3 * C_;
    const __hip_bfloat16* base = qkv + (size_t)b * L_ * stride + h * D_;

    short8 qf[2];
    {
        const __hip_bfloat16* qrow = base + (size_t)(q_blk + w * 16 + l16) * stride;
        qf[0] = *(const short8*)(qrow + quad * 8);
        qf[1] = *(const short8*)(qrow + 32 + quad * 8);
    }
    short8 ones;
#pragma unroll
    for (int j = 0; j < 8; ++j) ones[j] = (short)0x3F80;   // bf16 1.0

    float4v o_acc[4];
    float4v l_acc = (float4v){0.f, 0.f, 0.f, 0.f};
#pragma unroll
    for (int dt = 0; dt < 4; ++dt) o_acc[dt] = (float4v){0.f, 0.f, 0.f, 0.f};

    // staging: 512 threads → one 16B chunk each for K and V^T
    const int s_row = t >> 3;               // 0..63 (key row for K, d row for V^T)
    const int s_col = (t & 7) * 8;          // shorts
    const __hip_bfloat16* kg = base + C_;
    const short* vtb = vt + (size_t)bh * D_ * L_;

    // prologue: tile 0 → buf 0
    short8 kreg = *(const short8*)(kg + (size_t)s_row * stride + s_col);
    short8 vreg = *(const short8*)(vtb + (size_t)s_row * L_ + s_col);
    *(short8*)&K_lds[0][s_row * 72 + s_col] = kreg;
    *(short8*)&V_lds[0][s_row * 72 + s_col] = vreg;
    __syncthreads();

    for (int kt = 0, cur = 0; kt < L_; kt += 64, cur ^= 1) {
        const int nxt = kt + 64;
        if (nxt < L_) {   // T14: issue next-tile global loads BEFORE compute
            kreg = *(const short8*)(kg + (size_t)(nxt + s_row) * stride + s_col);
            vreg = *(const short8*)(vtb + (size_t)s_row * L_ + nxt + s_col);
        }

        // ---- S = Q K^T ----
        float4v sacc[4];
        __builtin_amdgcn_s_setprio(1);
#pragma unroll
        for (int kb = 0; kb < 4; ++kb) {
            sacc[kb] = (float4v){0.f, 0.f, 0.f, 0.f};
            short8 kf0 = *(const short8*)(&K_lds[cur][(kb * 16 + l16) * 72 + quad * 8]);
            short8 kf1 = *(const short8*)(&K_lds[cur][(kb * 16 + l16) * 72 + 32 + quad * 8]);
            sacc[kb] = __builtin_amdgcn_mfma_f32_16x16x32_bf16(qf[0], kf0, sacc[kb], 0, 0, 0);
            sacc[kb] = __builtin_amdgcn_mfma_f32_16x16x32_bf16(qf[1], kf1, sacc[kb], 0, 0, 0);
        }
        __builtin_amdgcn_s_setprio(0);

        // ---- p = exp(s/8 - SHIFT); no reductions ----
#pragma unroll
        for (int r = 0; r < 4; ++r) {
            short* prow = &P_lds[w][(quad * 4 + r) * 72];
            prow[l16]      = f2bs(__expf(fmaf(sacc[0][r], 0.125f, -8.f)));
            prow[16 + l16] = f2bs(__expf(fmaf(sacc[1][r], 0.125f, -8.f)));
            prow[32 + l16] = f2bs(__expf(fmaf(sacc[2][r], 0.125f, -8.f)));
            prow[48 + l16] = f2bs(__expf(fmaf(sacc[3][r], 0.125f, -8.f)));
        }

        // ---- O += P V ; l += P · 1 ----
        short8 pf0 = *(const short8*)(&P_lds[w][l16 * 72 + quad * 8]);
        short8 pf1 = *(const short8*)(&P_lds[w][l16 * 72 + 32 + quad * 8]);
        __builtin_amdgcn_s_setprio(1);
        l_acc = __builtin_amdgcn_mfma_f32_16x16x32_bf16(pf0, ones, l_acc, 0, 0, 0);
        l_acc = __builtin_amdgcn_mfma_f32_16x16x32_bf16(pf1, ones, l_acc, 0, 0, 0);
#pragma unroll
        for (int dt = 0; dt < 4; ++dt) {
            short8 vf0 = *(const short8*)(&V_lds[cur][(dt * 16 + l16) * 72 + quad * 8]);
            short8 vf1 = *(const short8*)(&V_lds[cur][(dt * 16 + l16) * 72 + 32 + quad * 8]);
            o_acc[dt] = __builtin_amdgcn_mfma_f32_16x16x32_bf16(pf0, vf0, o_acc[dt], 0, 0, 0);
            o_acc[dt] = __builtin_amdgcn_mfma_f32_16x16x32_bf16(pf1, vf1, o_acc[dt], 0, 0, 0);
        }
        __builtin_amdgcn_s_setprio(0);

        // write next tile into the ALTERNATE buffer (safe: other waves read
        // buf[cur] this tile; buf[cur^1] readers all passed last tile's barrier)
        if (nxt < L_) {
            *(short8*)&K_lds[cur ^ 1][s_row * 72 + s_col] = kreg;
            *(short8*)&V_lds[cur ^ 1][s_row * 72 + s_col] = vreg;
        }
        __syncthreads();
    }

#pragma unroll
    for (int dt = 0; dt < 4; ++dt)
#pragma unroll
        for (int r = 0; r < 4; ++r) {
            int q = q_blk + w * 16 + quad * 4 + r;
            o[(size_t)(b * L_ + q) * C_ + h * D_ + dt * 16 + l16] =
                __float2bfloat16(o_acc[dt][r] / l_acc[r]);
        }
}

// ---------------------------------------------------------------------------
extern "C" void kernel_launch(void* const* d_in, const int* in_sizes, int n_in,
                              void* d_out, int out_size, void* d_ws, size_t ws_size,
                              hipStream_t stream) {
    const float* feats  = (const float*)d_in[0];
    const float* mod    = (const float*)d_in[1];
    const float* w_mod  = (const float*)d_in[2];
    const float* b_mod  = (const float*)d_in[3];
    const float* w_qkv  = (const float*)d_in[4];
    const float* b_qkv  = (const float*)d_in[5];
    const float* w_proj = (const float*)d_in[6];
    const float* b_proj = (const float*)d_in[7];
    const float* w_fc1  = (const float*)d_in[8];
    const float* b_fc1  = (const float*)d_in[9];
    const float* w_fc2  = (const float*)d_in[10];
    const float* b_fc2  = (const float*)d_in[11];

    const int M = B_ * L_;          // 4096
    char* ws = (char*)d_ws;
    float* m_ws = (float*)ws;

    // Layout (~88.05 MB):
    //   m 48K | wT 24MB | slotB 24MB (qkv bf16 → x1 fp32 16MB) |
    //   slotA 8MB (h1/o/h2) | hf 32MB bf16 (doubles as VT 8MB during attn)
    short* wqkvT  = (short*)(ws + 49152);
    short* wprojT = wqkvT + (size_t)3 * C_ * C_;
    short* wfc1T  = wprojT + (size_t)C_ * C_;
    short* wfc2T  = wfc1T + (size_t)4 * C_ * C_;
    char* slotB = (char*)(wfc2T + (size_t)4 * C_ * C_);
    __hip_bfloat16* qkv_ws = (__hip_bfloat16*)slotB;
    float* x1_ws           = (float*)slotB;
    __hip_bfloat16* slotA  = (__hip_bfloat16*)(slotB + (size_t)M * 3 * C_ * 2);
    __hip_bfloat16* hf_ws  = slotA + (size_t)M * C_;
    short* vt_ws           = (short*)hf_ws;   // 8MB, dead outside step 4

    // 0. weight prep (bf16, transposed [N][K]) — single fused launch
    k_wt_all<<<3072, 256, 0, stream>>>(w_qkv, w_proj, w_fc1, w_fc2,
                                       wqkvT, wprojT, wfc1T, wfc2T);
    // 1. modulation vectors
    hipMemsetAsync(m_ws, 0, 2 * 6 * C_ * sizeof(float), stream);
    k_mod2<<<dim3(24, 4), 256, 0, stream>>>(mod, w_mod, b_mod, m_ws);
    // 2. h1 = modulate(LN(feats))
    k_ln_mod<<<M, 256, 0, stream>>>(feats, m_ws, 0, 1024, slotA);
    // 3. qkv = h1 @ w_qkv + b_qkv
    k_gemm_async<2, 2, 4, 4><<<dim3(3 * C_ / 128, M / 128), 256, 0, stream>>>(
        slotA, C_, wqkvT, C_, b_qkv, M, 3 * C_, C_, 0, 0,
        nullptr, nullptr, qkv_ws, nullptr);
    // 4. V^T precompute + attention (512 thr / 8 waves, q_blk=128)
    k_vt<<<dim3(L_ / 64, B_ * H_), 256, 0, stream>>>(qkv_ws, vt_ws);
    k_attn<<<B_ * H_ * (L_ / 128), 512, 0, stream>>>(qkv_ws, vt_ws, slotA);
    // 5. x1 = feats + (o @ w_proj + b_proj) * g_a
    k_gemm_async<4, 1, 2, 4><<<dim3(C_ / 64, M / 128), 256, 0, stream>>>(
        slotA, C_, wprojT, C_, b_proj, M, C_, C_, 0, 2,
        m_ws + 2 * C_, feats, nullptr, x1_ws);
    // 6. h2 = modulate(LN(x1))
    k_ln_mod<<<M, 256, 0, stream>>>(x1_ws, m_ws, 3 * C_, 4 * C_, slotA);
    // 7. hf = gelu(h2 @ w_fc1 + b_fc1)
    k_gemm_async<2, 2, 4, 4><<<dim3(4 * C_ / 128, M / 128), 256, 0, stream>>>(
        slotA, C_, wfc1T, C_, b_fc1, M, 4 * C_, C_, 1, 0,
        nullptr, nullptr, hf_ws, nullptr);
    // 8. out = x1 + (hf @ w_fc2 + b_fc2) * g_m
    k_gemm_async<4, 1, 2, 4><<<dim3(C_ / 64, M / 128), 256, 0, stream>>>(
        hf_ws, 4 * C_, wfc2T, 4 * C_, b_fc2, M, C_, 4 * C_, 0, 2,
        m_ws + 5 * C_, x1_ws, nullptr, (float*)d_out);
}

// Round 5
// 428.766 us; speedup vs baseline: 1.2113x; 1.2113x over previous
//
#include <hip/hip_runtime.h>
#include <hip/hip_bf16.h>
#include <math.h>

#define B_ 2
#define L_ 2048
#define C_ 1024
#define H_ 16
#define D_ 64

typedef __attribute__((ext_vector_type(8))) short short8;   // 8 bf16 = 16B
typedef __attribute__((ext_vector_type(4))) float float4v;

__device__ inline short f2bs(float f) {
    union { __hip_bfloat16 h; short s; } u; u.h = __float2bfloat16(f); return u.s;
}

// async 16B global→LDS DMA (dest = wave-uniform base + lane*16)
#define GL2LDS(gp, lp)                                                         \
    __builtin_amdgcn_global_load_lds(                                          \
        (const __attribute__((address_space(1))) void*)(gp),                   \
        (__attribute__((address_space(3))) void*)(lp), 16, 0, 0)

// ---------------------------------------------------------------------------
// k_mod2: m = silu(mod) @ w_mod + b_mod, split-K (4 segs of 256) + atomicAdd.
__global__ __launch_bounds__(256) void k_mod2(const float* __restrict__ mod,
                                              const float* __restrict__ w_mod,
                                              const float* __restrict__ b_mod,
                                              float* __restrict__ m_out) {
    __shared__ float a_s[2][256];
    const int t = threadIdx.x;
    const int seg = blockIdx.y;
    for (int i = t; i < 512; i += 256) {
        float a = mod[(i >> 8) * C_ + seg * 256 + (i & 255)];
        a_s[i >> 8][i & 255] = a / (1.f + __expf(-a));  // silu
    }
    __syncthreads();
    int j = blockIdx.x * 256 + t;  // 0..6143
    float acc0 = (seg == 0) ? b_mod[j] : 0.f;
    float acc1 = acc0;
    for (int k = 0; k < 256; ++k) {
        float w = w_mod[(size_t)(seg * 256 + k) * (6 * C_) + j];
        acc0 += a_s[0][k] * w;
        acc1 += a_s[1][k] * w;
    }
    atomicAdd(&m_out[j], acc0);
    atomicAdd(&m_out[6 * C_ + j], acc1);
}

// ---------------------------------------------------------------------------
// k_wt_all: all four weight transposes (fp32 [K][N] → bf16 [N][K]) in ONE
// launch. Flat grid of 3072 64x64 tiles: [0,768) qkv | [768,1024) proj |
// [1024,2048) fc1 | [2048,3072) fc2.
__global__ __launch_bounds__(256) void k_wt_all(
        const float* __restrict__ w_qkv, const float* __restrict__ w_proj,
        const float* __restrict__ w_fc1, const float* __restrict__ w_fc2,
        short* __restrict__ wqkvT, short* __restrict__ wprojT,
        short* __restrict__ wfc1T, short* __restrict__ wfc2T) {
    __shared__ short T[64][72];
    int id = blockIdx.x;
    const float* W; short* WT; int K, N;
    if (id < 768)       {             W = w_qkv;  WT = wqkvT;  K = C_;     N = 3 * C_; }
    else if (id < 1024) { id -= 768;  W = w_proj; WT = wprojT; K = C_;     N = C_;     }
    else if (id < 2048) { id -= 1024; W = w_fc1;  WT = wfc1T;  K = C_;     N = 4 * C_; }
    else                { id -= 2048; W = w_fc2;  WT = wfc2T;  K = 4 * C_; N = C_;     }
    const int nb = N >> 6;
    const int n0 = (id % nb) * 64, k0 = (id / nb) * 64;
    const int t = threadIdx.x;
    {
        int kr = t >> 2, nc = (t & 3) * 16;
        const float* src = W + (size_t)(k0 + kr) * N + n0 + nc;
#pragma unroll
        for (int j = 0; j < 16; ++j) T[kr][nc + j] = f2bs(src[j]);
    }
    __syncthreads();
    {
        int nr = t >> 2, kc = (t & 3) * 16;
        short8 o0, o1;
#pragma unroll
        for (int j = 0; j < 8; ++j) { o0[j] = T[kc + j][nr]; o1[j] = T[kc + 8 + j][nr]; }
        short* dst = WT + (size_t)(n0 + nr) * K + k0 + kc;
        *(short8*)dst = o0;
        *(short8*)(dst + 8) = o1;
    }
}

// ---------------------------------------------------------------------------
// k_vt: per-head V transpose. qkv [4096,3072] → vt [bh=32][d=64][L=2048] bf16.
__global__ __launch_bounds__(256) void k_vt(const __hip_bfloat16* __restrict__ qkv,
                                            short* __restrict__ vt) {
    __shared__ short T[64][72];
    const int t = threadIdx.x;
    const int kt = blockIdx.x * 64;
    const int bh = blockIdx.y;
    const int h = bh & (H_ - 1), b = bh >> 4;
    const __hip_bfloat16* src = qkv + ((size_t)(b * L_ + kt)) * (3 * C_) + 2 * C_ + h * D_;
    {
        int kr = t >> 2, dg = (t & 3) * 16;
        const short8* s = (const short8*)(src + (size_t)kr * (3 * C_) + dg);
        *(short8*)&T[kr][dg] = s[0];
        *(short8*)&T[kr][dg + 8] = s[1];
    }
    __syncthreads();
    {
        int dr = t >> 2, kg = (t & 3) * 16;
        short8 o0, o1;
#pragma unroll
        for (int j = 0; j < 8; ++j) { o0[j] = T[kg + j][dr]; o1[j] = T[kg + 8 + j][dr]; }
        short* dst = vt + ((size_t)bh * D_ + dr) * L_ + kt + kg;
        *(short8*)dst = o0;
        *(short8*)(dst + 8) = o1;
    }
}

// ---------------------------------------------------------------------------
// Kernel 2: LayerNorm (eps 1e-6, no affine) + adaLN modulate → bf16 h
__global__ __launch_bounds__(256) void k_ln_mod(const float* __restrict__ x,
                                                const float* __restrict__ mvec,
                                                int off_sh, int off_sc,
                                                __hip_bfloat16* __restrict__ h_out) {
    int row = blockIdx.x;       // 0..4095
    int b = row / L_;
    int t = threadIdx.x;
    float v[4];
    float s = 0.f, ss = 0.f;
#pragma unroll
    for (int i = 0; i < 4; ++i) {
        int c = t + i * 256;
        float val = x[(size_t)row * C_ + c];
        v[i] = val; s += val; ss += val * val;
    }
#pragma unroll
    for (int o = 32; o; o >>= 1) { s += __shfl_xor(s, o); ss += __shfl_xor(ss, o); }
    __shared__ float red[2][4];
    int wid = t >> 6, lane = t & 63;
    if (lane == 0) { red[0][wid] = s; red[1][wid] = ss; }
    __syncthreads();
    s  = red[0][0] + red[0][1] + red[0][2] + red[0][3];
    ss = red[1][0] + red[1][1] + red[1][2] + red[1][3];
    float mean = s * (1.f / C_);
    float var  = ss * (1.f / C_) - mean * mean;
    float rstd = rsqrtf(var + 1e-6f);
#pragma unroll
    for (int i = 0; i < 4; ++i) {
        int c = t + i * 256;
        float sc = mvec[b * (6 * C_) + off_sc + c];
        float sh = mvec[b * (6 * C_) + off_sh + c];
        float hn = (v[i] - mean) * rstd;
        h_out[(size_t)row * C_ + c] = __float2bfloat16(hn * (1.f + sc) + sh);
    }
}

// ---------------------------------------------------------------------------
// Shared GEMM epilogue
__device__ inline void gemm_epilogue(float v, int m, int n, int N, int act, int emode,
                                     const float* __restrict__ gate,
                                     const float* __restrict__ resid_f,
                                     __hip_bfloat16* __restrict__ out_bf,
                                     float* __restrict__ out_f) {
    if (act == 1) v = 0.5f * v * (1.f + erff(v * 0.70710678118654752440f));
    if (emode == 2) {
        float g = gate[(m >> 11) * (6 * C_) + n];
        v = resid_f[(size_t)m * N + n] + v * g;
    }
    if (out_f) out_f[(size_t)m * N + n] = v;
    else       out_bf[(size_t)m * N + n] = __float2bfloat16(v);
}

// ---------------------------------------------------------------------------
// k_gemm_async: A[M,K](bf16) @ WT[N,K](bf16 pre-transposed).
// v6 (this round): round-2 pipeline (best measured: dbuf BK=64, prefetch the
// next tile's global_load_lds at the TOP of the iteration, ONE __syncthreads
// per K-step) + two occupancy/locality levers:
//   * 512 threads / 8 waves per block (was 256/4): same tile, same LDS, same
//     grid → 16 waves/CU instead of 8. The profile is stall-dominated
//     (MfmaUtil 16%, VALU 31%, Occ 21%) — TLP is the cover.
//   * T1 bijective XCD-chunk swizzle on the linearized block id: the 16-32
//     n-blocks sharing an A m-panel become contiguous on ONE XCD's L2
//     (R3 counters: fc2 FETCH 143MB from cross-XCD panel re-fetch).
// LDS rows = 64 shorts = 8×16B chunks, XOR-swizzled (phys = logical^(row&7))
// → conflict-free b128 frag reads (verified 0 conflicts R2/R4) and
// DMA-compatible staging. Wave grid WM×WN (8 waves), per-wave MI×NI 16×16
// frags. All grids are multiples of 8 blocks.
template<int WM, int WN, int MI, int NI>
__global__ __launch_bounds__(512) void k_gemm_async(
        const __hip_bfloat16* __restrict__ A, int lda,
        const short* __restrict__ WT, int ldw,
        const float* __restrict__ bias,
        int M, int N, int K, int act, int emode,
        const float* __restrict__ gate,
        const float* __restrict__ resid_f,
        __hip_bfloat16* __restrict__ out_bf,
        float* __restrict__ out_f) {
    constexpr int BM = WM * MI * 16;
    constexpr int BN = WN * NI * 16;
    __shared__ __align__(16) short A_lds[2][BM * 64];
    __shared__ __align__(16) short B_lds[2][BN * 64];
    const int t = threadIdx.x;
    const int lane = t & 63;
    const int w = t >> 6;                   // 0..7
    const int wm = w / WN, wn = w % WN;
    const int quad = lane >> 4, l16 = lane & 15;

    // T1: bijective XCD-chunk swizzle (all call sites have nwg % 8 == 0).
    const int gx = gridDim.x;
    const int nwg = gx * gridDim.y;
    const int lin = blockIdx.y * gx + blockIdx.x;
    const int wg = (lin & 7) * (nwg >> 3) + (lin >> 3);
    const int m0 = (wg / gx) * BM;
    const int n0 = (wg % gx) * BN;

    auto stage = [&](int buf, int k0) {
#pragma unroll
        for (int rep = 0; rep < BM / 64; ++rep) {
            int p = rep * 512 + t;                 // phys chunk id
            int row = p >> 3;
            int g = (p & 7) ^ (row & 7);           // logical k-group
            const __hip_bfloat16* gp = A + (size_t)(m0 + row) * lda + k0 + g * 8;
            GL2LDS(gp, &A_lds[buf][(rep * 512 + (t & ~63)) * 8]);
        }
#pragma unroll
        for (int rep = 0; rep < BN / 64; ++rep) {
            int p = rep * 512 + t;
            int row = p >> 3;
            int g = (p & 7) ^ (row & 7);
            const short* gp = WT + (size_t)(n0 + row) * ldw + k0 + g * 8;
            GL2LDS(gp, &B_lds[buf][(rep * 512 + (t & ~63)) * 8]);
        }
    };

    float4v acc[MI][NI] = {};

    // prologue: tile 0 → buf 0
    stage(0, 0);
    __syncthreads();           // vmcnt(0) drain + all waves see buf 0

    const int nt = K >> 6;
    int cur = 0;
    for (int kt = 0; kt < nt; ++kt) {
        // prefetch next tile BEFORE compute (into the other buffer; its
        // readers all passed the previous iteration's barrier)
        if (kt + 1 < nt) stage(cur ^ 1, (kt + 1) << 6);

        // ---- fragments + MFMA (two k-halves) from buf[cur] ----
        short8 af[MI][2], bfr[NI][2];
#pragma unroll
        for (int mi = 0; mi < MI; ++mi) {
            int r = wm * MI * 16 + mi * 16 + l16;
#pragma unroll
            for (int hh = 0; hh < 2; ++hh)
                af[mi][hh] = *(const short8*)(&A_lds[cur][(r * 8 + ((hh * 4 + quad) ^ (r & 7))) * 8]);
        }
#pragma unroll
        for (int ni = 0; ni < NI; ++ni) {
            int r = wn * NI * 16 + ni * 16 + l16;
#pragma unroll
            for (int hh = 0; hh < 2; ++hh)
                bfr[ni][hh] = *(const short8*)(&B_lds[cur][(r * 8 + ((hh * 4 + quad) ^ (r & 7))) * 8]);
        }
#pragma unroll
        for (int hh = 0; hh < 2; ++hh)
#pragma unroll
            for (int mi = 0; mi < MI; ++mi)
#pragma unroll
                for (int ni = 0; ni < NI; ++ni)
                    acc[mi][ni] = __builtin_amdgcn_mfma_f32_16x16x32_bf16(
                        af[mi][hh], bfr[ni][hh], acc[mi][ni], 0, 0, 0);

        // single barrier per K-step: implicit vmcnt(0) drains the prefetch
        // (in flight across the whole compute phase), and fences buf reuse.
        __syncthreads();
        cur ^= 1;
    }

#pragma unroll
    for (int mi = 0; mi < MI; ++mi)
#pragma unroll
        for (int ni = 0; ni < NI; ++ni)
#pragma unroll
            for (int r = 0; r < 4; ++r) {
                int m = m0 + wm * MI * 16 + mi * 16 + quad * 4 + r;
                int n = n0 + wn * NI * 16 + ni * 16 + l16;
                float v = acc[mi][ni][r] + (bias ? bias[n] : 0.f);
                gemm_epilogue(v, m, n, N, act, emode, gate, resid_f, out_bf, out_f);
            }
}

// ---------------------------------------------------------------------------
// Kernel 4: flash attention, MFMA, shift-softmax (no max tracking: constant
// shift cancels in Σpv/Σp; scores bounded |s|≲6 ⇒ no overflow). Row-sums l
// via extra MFMA against all-ones B-frag.
//
// 512 threads / 8 waves, q_blk=128, double-buffered K/V LDS with T14
// async-stage split: next-tile K/V chunks loaded into REGISTERS at the top
// of the tile (global latency hides under QK/softmax/PV), written to the
// alternate LDS buffer after compute, ONE barrier per tile. All LDS strides
// = 72 shorts (144B, 16B-aligned rows → true ds_read_b128). Grid 512 =
// 2 blocks/CU, XCD-chunked block swizzle for L2 locality.
__global__ __launch_bounds__(512) void k_attn(const __hip_bfloat16* __restrict__ qkv,
                                              const short* __restrict__ vt,
                                              __hip_bfloat16* __restrict__ o) {
    __shared__ __align__(16) short K_lds[2][64 * 72];   // [buf][key][d]
    __shared__ __align__(16) short V_lds[2][64 * 72];   // [buf][d][key]
    __shared__ __align__(16) short P_lds[8][16 * 72];   // per wave: [q][key]
    const int t = threadIdx.x;
    const int lane = t & 63;
    const int w = t >> 6;                   // 0..7
    const int quad = lane >> 4, l16 = lane & 15;

    // XCD-chunked bijective swizzle: 512 wgs, 8 XCDs, 64 contiguous per XCD.
    const int raw = blockIdx.x;
    const int blk = (raw & 7) * 64 + (raw >> 3);
    const int bh = blk >> 4;                // 0..31 (4 bh per XCD chunk)
    const int q_blk = (blk & 15) * 128;
    const int h = bh & (H_ - 1);
    const int b = bh >> 4;

    const size_t stride = 3 * C_;
    const __hip_bfloat16* base = qkv + (size_t)b * L_ * stride + h * D_;

    short8 qf[2];
    {
        const __hip_bfloat16* qrow = base + (size_t)(q_blk + w * 16 + l16) * stride;
        qf[0] = *(const short8*)(qrow + quad * 8);
        qf[1] = *(const short8*)(qrow + 32 + quad * 8);
    }
    short8 ones;
#pragma unroll
    for (int j = 0; j < 8; ++j) ones[j] = (short)0x3F80;   // bf16 1.0

    float4v o_acc[4];
    float4v l_acc = (float4v){0.f, 0.f, 0.f, 0.f};
#pragma unroll
    for (int dt = 0; dt < 4; ++dt) o_acc[dt] = (float4v){0.f, 0.f, 0.f, 0.f};

    // staging: 512 threads → one 16B chunk each for K and V^T
    const int s_row = t >> 3;               // 0..63 (key row for K, d row for V^T)
    const int s_col = (t & 7) * 8;          // shorts
    const __hip_bfloat16* kg = base + C_;
    const short* vtb = vt + (size_t)bh * D_ * L_;

    // prologue: tile 0 → buf 0
    short8 kreg = *(const short8*)(kg + (size_t)s_row * stride + s_col);
    short8 vreg = *(const short8*)(vtb + (size_t)s_row * L_ + s_col);
    *(short8*)&K_lds[0][s_row * 72 + s_col] = kreg;
    *(short8*)&V_lds[0][s_row * 72 + s_col] = vreg;
    __syncthreads();

    for (int kt = 0, cur = 0; kt < L_; kt += 64, cur ^= 1) {
        const int nxt = kt + 64;
        if (nxt < L_) {   // T14: issue next-tile global loads BEFORE compute
            kreg = *(const short8*)(kg + (size_t)(nxt + s_row) * stride + s_col);
            vreg = *(const short8*)(vtb + (size_t)s_row * L_ + nxt + s_col);
        }

        // ---- S = Q K^T ----
        float4v sacc[4];
        __builtin_amdgcn_s_setprio(1);
#pragma unroll
        for (int kb = 0; kb < 4; ++kb) {
            sacc[kb] = (float4v){0.f, 0.f, 0.f, 0.f};
            short8 kf0 = *(const short8*)(&K_lds[cur][(kb * 16 + l16) * 72 + quad * 8]);
            short8 kf1 = *(const short8*)(&K_lds[cur][(kb * 16 + l16) * 72 + 32 + quad * 8]);
            sacc[kb] = __builtin_amdgcn_mfma_f32_16x16x32_bf16(qf[0], kf0, sacc[kb], 0, 0, 0);
            sacc[kb] = __builtin_amdgcn_mfma_f32_16x16x32_bf16(qf[1], kf1, sacc[kb], 0, 0, 0);
        }
        __builtin_amdgcn_s_setprio(0);

        // ---- p = exp(s/8 - SHIFT); no reductions ----
#pragma unroll
        for (int r = 0; r < 4; ++r) {
            short* prow = &P_lds[w][(quad * 4 + r) * 72];
            prow[l16]      = f2bs(__expf(fmaf(sacc[0][r], 0.125f, -8.f)));
            prow[16 + l16] = f2bs(__expf(fmaf(sacc[1][r], 0.125f, -8.f)));
            prow[32 + l16] = f2bs(__expf(fmaf(sacc[2][r], 0.125f, -8.f)));
            prow[48 + l16] = f2bs(__expf(fmaf(sacc[3][r], 0.125f, -8.f)));
        }

        // ---- O += P V ; l += P · 1 ----
        short8 pf0 = *(const short8*)(&P_lds[w][l16 * 72 + quad * 8]);
        short8 pf1 = *(const short8*)(&P_lds[w][l16 * 72 + 32 + quad * 8]);
        __builtin_amdgcn_s_setprio(1);
        l_acc = __builtin_amdgcn_mfma_f32_16x16x32_bf16(pf0, ones, l_acc, 0, 0, 0);
        l_acc = __builtin_amdgcn_mfma_f32_16x16x32_bf16(pf1, ones, l_acc, 0, 0, 0);
#pragma unroll
        for (int dt = 0; dt < 4; ++dt) {
            short8 vf0 = *(const short8*)(&V_lds[cur][(dt * 16 + l16) * 72 + quad * 8]);
            short8 vf1 = *(const short8*)(&V_lds[cur][(dt * 16 + l16) * 72 + 32 + quad * 8]);
            o_acc[dt] = __builtin_amdgcn_mfma_f32_16x16x32_bf16(pf0, vf0, o_acc[dt], 0, 0, 0);
            o_acc[dt] = __builtin_amdgcn_mfma_f32_16x16x32_bf16(pf1, vf1, o_acc[dt], 0, 0, 0);
        }
        __builtin_amdgcn_s_setprio(0);

        // write next tile into the ALTERNATE buffer (safe: other waves read
        // buf[cur] this tile; buf[cur^1] readers all passed last tile's barrier)
        if (nxt < L_) {
            *(short8*)&K_lds[cur ^ 1][s_row * 72 + s_col] = kreg;
            *(short8*)&V_lds[cur ^ 1][s_row * 72 + s_col] = vreg;
        }
        __syncthreads();
    }

#pragma unroll
    for (int dt = 0; dt < 4; ++dt)
#pragma unroll
        for (int r = 0; r < 4; ++r) {
            int q = q_blk + w * 16 + quad * 4 + r;
            o[(size_t)(b * L_ + q) * C_ + h * D_ + dt * 16 + l16] =
                __float2bfloat16(o_acc[dt][r] / l_acc[r]);
        }
}

// ---------------------------------------------------------------------------
extern "C" void kernel_launch(void* const* d_in, const int* in_sizes, int n_in,
                              void* d_out, int out_size, void* d_ws, size_t ws_size,
                              hipStream_t stream) {
    const float* feats  = (const float*)d_in[0];
    const float* mod    = (const float*)d_in[1];
    const float* w_mod  = (const float*)d_in[2];
    const float* b_mod  = (const float*)d_in[3];
    const float* w_qkv  = (const float*)d_in[4];
    const float* b_qkv  = (const float*)d_in[5];
    const float* w_proj = (const float*)d_in[6];
    const float* b_proj = (const float*)d_in[7];
    const float* w_fc1  = (const float*)d_in[8];
    const float* b_fc1  = (const float*)d_in[9];
    const float* w_fc2  = (const float*)d_in[10];
    const float* b_fc2  = (const float*)d_in[11];

    const int M = B_ * L_;          // 4096
    char* ws = (char*)d_ws;
    float* m_ws = (float*)ws;

    // Layout (~88.05 MB):
    //   m 48K | wT 24MB | slotB 24MB (qkv bf16 → x1 fp32 16MB) |
    //   slotA 8MB (h1/o/h2) | hf 32MB bf16 (doubles as VT 8MB during attn)
    short* wqkvT  = (short*)(ws + 49152);
    short* wprojT = wqkvT + (size_t)3 * C_ * C_;
    short* wfc1T  = wprojT + (size_t)C_ * C_;
    short* wfc2T  = wfc1T + (size_t)4 * C_ * C_;
    char* slotB = (char*)(wfc2T + (size_t)4 * C_ * C_);
    __hip_bfloat16* qkv_ws = (__hip_bfloat16*)slotB;
    float* x1_ws           = (float*)slotB;
    __hip_bfloat16* slotA  = (__hip_bfloat16*)(slotB + (size_t)M * 3 * C_ * 2);
    __hip_bfloat16* hf_ws  = slotA + (size_t)M * C_;
    short* vt_ws           = (short*)hf_ws;   // 8MB, dead outside step 4

    // 0. weight prep (bf16, transposed [N][K]) — single fused launch
    k_wt_all<<<3072, 256, 0, stream>>>(w_qkv, w_proj, w_fc1, w_fc2,
                                       wqkvT, wprojT, wfc1T, wfc2T);
    // 1. modulation vectors
    hipMemsetAsync(m_ws, 0, 2 * 6 * C_ * sizeof(float), stream);
    k_mod2<<<dim3(24, 4), 256, 0, stream>>>(mod, w_mod, b_mod, m_ws);
    // 2. h1 = modulate(LN(feats))
    k_ln_mod<<<M, 256, 0, stream>>>(feats, m_ws, 0, 1024, slotA);
    // 3. qkv = h1 @ w_qkv + b_qkv   (128x128 tile, 8 waves)
    k_gemm_async<2, 4, 4, 2><<<dim3(3 * C_ / 128, M / 128), 512, 0, stream>>>(
        slotA, C_, wqkvT, C_, b_qkv, M, 3 * C_, C_, 0, 0,
        nullptr, nullptr, qkv_ws, nullptr);
    // 4. V^T precompute + attention (512 thr / 8 waves, q_blk=128)
    k_vt<<<dim3(L_ / 64, B_ * H_), 256, 0, stream>>>(qkv_ws, vt_ws);
    k_attn<<<B_ * H_ * (L_ / 128), 512, 0, stream>>>(qkv_ws, vt_ws, slotA);
    // 5. x1 = feats + (o @ w_proj + b_proj) * g_a   (128x64 tile, 8 waves)
    k_gemm_async<4, 2, 2, 2><<<dim3(C_ / 64, M / 128), 512, 0, stream>>>(
        slotA, C_, wprojT, C_, b_proj, M, C_, C_, 0, 2,
        m_ws + 2 * C_, feats, nullptr, x1_ws);
    // 6. h2 = modulate(LN(x1))
    k_ln_mod<<<M, 256, 0, stream>>>(x1_ws, m_ws, 3 * C_, 4 * C_, slotA);
    // 7. hf = gelu(h2 @ w_fc1 + b_fc1)   (128x128 tile, 8 waves)
    k_gemm_async<2, 4, 4, 2><<<dim3(4 * C_ / 128, M / 128), 512, 0, stream>>>(
        slotA, C_, wfc1T, C_, b_fc1, M, 4 * C_, C_, 1, 0,
        nullptr, nullptr, hf_ws, nullptr);
    // 8. out = x1 + (hf @ w_fc2 + b_fc2) * g_m   (128x64 tile, 8 waves)
    k_gemm_async<4, 2, 2, 2><<<dim3(C_ / 64, M / 128), 512, 0, stream>>>(
        hf_ws, 4 * C_, wfc2T, 4 * C_, b_fc2, M, C_, 4 * C_, 0, 2,
        m_ws + 5 * C_, x1_ws, nullptr, (float*)d_out);
}